// Round 3
// baseline (187.136 us; speedup 1.0000x reference)
//
#include <hip/hip_runtime.h>
#include <math.h>

// Problem constants (fixed by setup_inputs)
#define BSZ    2
#define LFULL  4096
#define MLEN   2048      // M = hidden_states.shape[1]
#define DMODEL 2048
#define CLIP_EPS 1e-4f
#define CCH    256       // number of chunks
#define TCH    8         // chunk length; CCH*TCH == MLEN

#define FLAG_MAGIC 0x13579BDFu

typedef float f4 __attribute__((ext_vector_type(4)));

// ---------------------------------------------------------------------------
// K1 body: boundary-mask stable partition + per-position decay params.
// Bit-identical to the verified standalone k1_prep.
// ---------------------------------------------------------------------------
__device__ __forceinline__ void k1_body(
    const int b, const int tid,
    const int* __restrict__ bmask_raw, const float* __restrict__ bprob,
    int* __restrict__ Ls, int* __restrict__ Le,
    float* __restrict__ wA, float* __restrict__ eA,
    float* __restrict__ cde, float* __restrict__ Pc,
    int* s_cnt /*257*/, int* s_meta /*2*/, int* s_sel /*MLEN*/, float* s_e /*MLEN*/)
{
  if (tid == 0) {
    unsigned w0 = ((const unsigned*)bmask_raw)[0];
    s_meta[0] = (w0 <= 1u) ? 1 : 0;  // 1: int32 per element, 0: uint8
  }
  __syncthreads();
  const int mode = s_meta[0];
  const unsigned char* bmask_u8 = (const unsigned char*)bmask_raw;

  const int PER = LFULL / 256;    // 16 positions per thread
  const int base = tid * PER;

  int cnt = 0;
  for (int i = 0; i < PER; ++i) {
    const int L = base + i;
    const int v = mode ? (bmask_raw[b * LFULL + L] != 0)
                       : (bmask_u8[b * LFULL + L] != 0);
    cnt += v;
  }
  s_cnt[tid] = cnt;
  __syncthreads();

  // Exclusive prefix over 256 counts: wave 0, lane i owns entries 4i..4i+3.
  if (tid < 64) {
    const int j = tid * 4;
    const int c0 = s_cnt[j], c1 = s_cnt[j + 1], c2 = s_cnt[j + 2], c3 = s_cnt[j + 3];
    const int mysum = c0 + c1 + c2 + c3;
    int incl = mysum;
    #pragma unroll
    for (int off = 1; off < 64; off <<= 1) {
      const int v = __shfl_up(incl, off, 64);
      if (tid >= off) incl += v;
    }
    const int excl = incl - mysum;
    s_cnt[j]     = excl;
    s_cnt[j + 1] = excl + c0;
    s_cnt[j + 2] = excl + c0 + c1;
    s_cnt[j + 3] = excl + c0 + c1 + c2;
    if (tid == 63) { s_cnt[256] = incl; s_meta[1] = incl; }
  }
  __syncthreads();
  const int ntrue = s_meta[1];

  // Fill sel: boundary positions (rank) then non-boundary (ntrue + false-rank)
  int trun = s_cnt[tid];
  for (int i = 0; i < PER; ++i) {
    const int L = base + i;
    const int v = mode ? (bmask_raw[b * LFULL + L] != 0)
                       : (bmask_u8[b * LFULL + L] != 0);
    if (v) {
      if (trun < MLEN) s_sel[trun] = L;
      ++trun;
    } else {
      const int f = L - trun;           // falses strictly before L
      const int slot = ntrue + f;
      if (slot < MLEN) s_sel[slot] = L;
    }
  }
  __syncthreads();

  // w, e per selected position
  for (int j = tid; j < MLEN; j += 256) {
    const int L = s_sel[j];
    float p = bprob[((size_t)b * LFULL + L) * 2 + 1];
    p = fminf(fmaxf(p, CLIP_EPS), 1.0f - CLIP_EPS);
    const float dt = -log1pf(-p);       // log(1/(1-p))
    wA[b * MLEN + j] = p / dt;
    const float e = 1.0f - p;           // exp(-dt) exactly
    eA[b * MLEN + j] = e;
    s_e[j] = e;
  }
  __syncthreads();

  // per-chunk cumulative decay + chunk product: one thread per chunk of 8
  {
    const int c = tid;                  // 256 chunks
    const int o = c * TCH;
    float run = 1.0f;
    #pragma unroll
    for (int i = 0; i < TCH; ++i) {
      run *= s_e[o + i];
      cde[b * MLEN + o + i] = run;
    }
    Pc[b * CCH + c] = run;
  }

  // scatter ranges: plug[L] = (#boundaries <= L) - 1, clamped to [0, M-1]
  const int nb = (ntrue < MLEN) ? ntrue : MLEN;
  for (int j = tid; j < MLEN; j += 256) {
    int ls, le;
    if (nb == 0) {
      ls = (j == 0) ? 0 : LFULL;
      le = (j == 0) ? LFULL : LFULL;
    } else if (j < nb) {
      ls = (j == 0) ? 0 : s_sel[j];
      le = (j == nb - 1) ? LFULL : s_sel[j + 1];
    } else {
      ls = LFULL; le = LFULL;           // empty
    }
    Ls[b * MLEN + j] = ls;
    Le[b * MLEN + j] = le;
  }
}

// ---------------------------------------------------------------------------
// K12: fused prep + per-chunk local scan.
// grid (2,256,2) = 1024 blocks = exactly the guaranteed-resident capacity
// (launch_bounds(256,4) => <=128 VGPR => >=4 blocks/CU; LDS 17.5KB => 9/CU),
// so the 2 producer blocks always run -> flag handshake cannot deadlock.
// All blocks issue hid loads into registers FIRST (33.5 MB in flight), then:
//   blocks flat 0,1: run k1_body, release-fence, publish MAGIC flag.
//   others: tid0 spins with s_sleep backoff, then acquire-fence.
// Numerics: bit-identical to the 4-kernel baseline.
// ---------------------------------------------------------------------------
__global__ __launch_bounds__(256, 4) void k12_fused(
    const float* __restrict__ hid, const int* __restrict__ bmask_raw,
    const float* __restrict__ bprob,
    int* __restrict__ Ls, int* __restrict__ Le,
    float* __restrict__ wA, float* __restrict__ eA,
    float* __restrict__ cde, float* __restrict__ Pc,
    float* __restrict__ S, unsigned* __restrict__ flags)
{
  const int tid = threadIdx.x;
  const int c = blockIdx.y;
  const int b = blockIdx.z;
  const int flat = (int)blockIdx.x +
                   (int)gridDim.x * ((int)blockIdx.y + (int)gridDim.y * (int)blockIdx.z);

  __shared__ union {
    struct { int cnt[257]; int meta[2]; int sel[MLEN]; float e[MLEN]; } k1;  // 17.4 KB
    struct { float w[TCH]; float e[TCH]; } k2;
  } sm;

  // ---- issue this chunk's hid loads; traffic flows during prep/spin ----
  const int d4 = blockIdx.x * 256 + tid;              // f4 lane in [0,512)
  const f4* xp = (const f4*)hid + ((size_t)(b * MLEN + c * TCH) * DMODEL >> 2) + d4;
  f4 xr[TCH];
  #pragma unroll
  for (int t = 0; t < TCH; ++t) xr[t] = xp[(size_t)t * (DMODEL / 4)];

  if (flat < BSZ) {
    // producer: prep for batch `flat`, then publish
    k1_body(flat, tid, bmask_raw, bprob, Ls, Le, wA, eA, cde, Pc,
            sm.k1.cnt, sm.k1.meta, sm.k1.sel, sm.k1.e);
    __threadfence();                                  // release: wb L2 to device
    __syncthreads();
    if (tid == 0)
      __hip_atomic_store(&flags[flat], FLAG_MAGIC, __ATOMIC_RELEASE,
                         __HIP_MEMORY_SCOPE_AGENT);
  } else {
    // consumer: wait for both producers (tid0 only, light polling)
    if (tid == 0) {
      int guard = 0;
      while ((__hip_atomic_load(&flags[0], __ATOMIC_RELAXED,
                                __HIP_MEMORY_SCOPE_AGENT) != FLAG_MAGIC ||
              __hip_atomic_load(&flags[1], __ATOMIC_RELAXED,
                                __HIP_MEMORY_SCOPE_AGENT) != FLAG_MAGIC) &&
             ++guard < (1 << 22)) {
        __builtin_amdgcn_s_sleep(8);
      }
    }
    __syncthreads();
    __threadfence();                                  // acquire: inv stale lines
  }
  __syncthreads();

  // ---- K2 role: per-chunk local scan -> chunk-final state S ----
  const int o = b * MLEN + c * TCH;
  if (tid < TCH)            sm.k2.w[tid]       = wA[o + tid];
  else if (tid < 2 * TCH)   sm.k2.e[tid - TCH] = eA[o + (tid - TCH)];
  __syncthreads();

  f4 st = {0.f, 0.f, 0.f, 0.f};
  #pragma unroll
  for (int t = 0; t < TCH; ++t) {
    const f4 x = xr[t];
    const float w = sm.k2.w[t], e = sm.k2.e[t];
    st.x = fmaf(e, st.x, w * x.x);
    st.y = fmaf(e, st.y, w * x.y);
    st.z = fmaf(e, st.z, w * x.z);
    st.w = fmaf(e, st.w, w * x.w);
  }
  ((f4*)S)[((size_t)(b * CCH + c) * DMODEL >> 2) + d4] = st;
}

// ---------------------------------------------------------------------------
// K2.5: cross-chunk exclusive scan, in place over S. (unchanged)
// grid: (DMODEL/4, BSZ) = (512, 2); 256 threads = 256 chunks
// ---------------------------------------------------------------------------
__global__ __launch_bounds__(256) void k25_scan(
    const float* __restrict__ Pc, float* __restrict__ S)
{
  const int c  = threadIdx.x;   // chunk index
  const int d4 = blockIdx.x;    // float4 lane in [0, DMODEL/4)
  const int b  = blockIdx.y;

  __shared__ float sP[CCH];
  __shared__ f4    sS[CCH];

  f4* Sf4 = (f4*)S;
  const size_t idx = ((size_t)(b * CCH + c) * DMODEL >> 2) + d4;

  sP[c] = Pc[b * CCH + c];
  sS[c] = Sf4[idx];
  __syncthreads();

  #pragma unroll
  for (int dstep = 1; dstep < CCH; dstep <<= 1) {
    float pd = 1.0f;
    f4 sd = {0.f, 0.f, 0.f, 0.f};
    if (c >= dstep) { pd = sP[c - dstep]; sd = sS[c - dstep]; }
    __syncthreads();
    if (c >= dstep) {
      f4 cur = sS[c];
      const float pc = sP[c];
      cur.x = fmaf(pc, sd.x, cur.x);
      cur.y = fmaf(pc, sd.y, cur.y);
      cur.z = fmaf(pc, sd.z, cur.z);
      cur.w = fmaf(pc, sd.w, cur.w);
      sS[c] = cur;
      sP[c] = pc * pd;
    }
    __syncthreads();
  }

  // exclusive shift: carry-in for chunk c is inclusive scan at c-1
  f4 g = {0.f, 0.f, 0.f, 0.f};
  if (c > 0) g = sS[c - 1];
  Sf4[idx] = g;
}

// ---------------------------------------------------------------------------
// K3: load carry-in G, redo local scan (hid L3-hot from K12), y = local +
//     cde*G, scatter to out rows [Ls, Le) with NT stores. (unchanged)
// grid: (2, CCH, BSZ) = 1024 blocks
// ---------------------------------------------------------------------------
__global__ __launch_bounds__(256) void k3_out(
    const float* __restrict__ hid, const float* __restrict__ wA,
    const float* __restrict__ eA, const float* __restrict__ cde,
    const float* __restrict__ G,
    const int* __restrict__ Ls, const int* __restrict__ Le,
    float* __restrict__ out)
{
  const int tid = threadIdx.x;
  const int c = blockIdx.y;
  const int b = blockIdx.z;

  __shared__ float s_w[TCH], s_e[TCH], s_c[TCH];
  __shared__ int   s_ls[TCH], s_le[TCH];
  const int o = b * MLEN + c * TCH;
  if (tid < TCH)          { s_w[tid] = wA[o + tid];  s_ls[tid] = Ls[o + tid]; }
  else if (tid < 2 * TCH) { const int t = tid - TCH;     s_e[t] = eA[o + t]; s_le[t] = Le[o + t]; }
  else if (tid < 3 * TCH) { const int t = tid - 2 * TCH; s_c[t] = cde[o + t]; }
  __syncthreads();

  const int d4 = blockIdx.x * 256 + tid;

  const f4 H = ((const f4*)G)[((size_t)(b * CCH + c) * DMODEL >> 2) + d4];

  const f4* xp = (const f4*)hid + ((size_t)(b * MLEN + c * TCH) * DMODEL >> 2) + d4;
  f4*       op = (f4*)out + ((size_t)b * LFULL * DMODEL >> 2) + d4;

  f4 st = {0.f, 0.f, 0.f, 0.f};
  #pragma unroll
  for (int t = 0; t < TCH; ++t) {
    const f4 x = xp[(size_t)t * (DMODEL / 4)];
    const float w = s_w[t], e = s_e[t], cd = s_c[t];
    st.x = fmaf(e, st.x, w * x.x);
    st.y = fmaf(e, st.y, w * x.y);
    st.z = fmaf(e, st.z, w * x.z);
    st.w = fmaf(e, st.w, w * x.w);
    f4 y;
    y.x = fmaf(cd, H.x, st.x);
    y.y = fmaf(cd, H.y, st.y);
    y.z = fmaf(cd, H.z, st.z);
    y.w = fmaf(cd, H.w, st.w);
    const int ls = s_ls[t], le = s_le[t];
    for (int L = ls; L < le; ++L) {
      __builtin_nontemporal_store(y, op + (size_t)L * (DMODEL / 4));
    }
  }
}

// ---------------------------------------------------------------------------
extern "C" void kernel_launch(void* const* d_in, const int* in_sizes, int n_in,
                              void* d_out, int out_size, void* d_ws, size_t ws_size,
                              hipStream_t stream) {
  const float* hid   = (const float*)d_in[0];   // (2, 2048, 2048) fp32
  const int*   bmask = (const int*)d_in[1];     // (2, 4096) bool (layout sniffed)
  const float* bprob = (const float*)d_in[2];   // (2, 4096, 2) fp32
  float*       out   = (float*)d_out;           // (2, 4096, 2048) fp32

  char* ws = (char*)d_ws;
  const size_t SZI = (size_t)BSZ * MLEN * sizeof(int);    // 16 KB
  const size_t SZF = (size_t)BSZ * MLEN * sizeof(float);  // 16 KB
  int*   Ls  = (int*)(ws);
  int*   Le  = (int*)(ws + SZI);
  float* wA  = (float*)(ws + 2 * SZI);
  float* eA  = (float*)(ws + 2 * SZI + SZF);
  float* cde = (float*)(ws + 2 * SZI + 2 * SZF);
  float* Pc  = (float*)(ws + 2 * SZI + 3 * SZF);          // 2 KB used
  float* S   = (float*)(ws + 2 * SZI + 3 * SZF + 4096);   // 4 MB
  unsigned* flags = (unsigned*)(ws + 2 * SZI + 3 * SZF + 4096 +
                                (size_t)BSZ * CCH * DMODEL * sizeof(float));

  dim3 grid(DMODEL / 1024, CCH, BSZ);   // (2, 256, 2) = 1024 blocks
  dim3 block(256);

  // fused prep + local chunk scan (flag handshake, no separate K1 dispatch)
  k12_fused<<<grid, block, 0, stream>>>(hid, bmask, bprob,
                                        Ls, Le, wA, eA, cde, Pc, S, flags);

  k25_scan<<<dim3(DMODEL / 4, BSZ), block, 0, stream>>>(Pc, S);

  k3_out<<<grid, block, 0, stream>>>(hid, wA, eA, cde, S, Ls, Le, out);
}

// Round 5
// 118.553 us; speedup vs baseline: 1.5785x; 1.5785x over previous
//
#include <hip/hip_runtime.h>
#include <math.h>

// Problem constants (fixed by setup_inputs)
#define BSZ    2
#define LFULL  4096
#define MLEN   2048      // M = hidden_states.shape[1]
#define DMODEL 2048
#define CLIP_EPS 1e-4f
#define CCH    256       // number of chunks
#define TCH    8         // chunk length; CCH*TCH == MLEN

typedef float f4 __attribute__((ext_vector_type(4)));

// ---------------------------------------------------------------------------
// K1: prep. One block per batch (grid = BSZ). Verified (R0 baseline) version.
//  - sniff boundary_mask dtype (int32 words vs packed uint8)
//  - stable-partition selection via block-wide prefix scan
//  - p -> w = p/dt (dt = -log1p(-p)), e = 1-p (== exp(-dt) exactly)
//  - per-chunk cumulative decay cde, chunk products Pc
//  - output scatter ranges [Ls[t], Le[t])
// ---------------------------------------------------------------------------
__global__ __launch_bounds__(256) void k1_prep(
    const int* __restrict__ bmask_raw, const float* __restrict__ bprob,
    int* __restrict__ Ls, int* __restrict__ Le,
    float* __restrict__ wA, float* __restrict__ eA,
    float* __restrict__ cde, float* __restrict__ Pc)
{
  const int b   = blockIdx.x;
  const int tid = threadIdx.x;

  __shared__ int   s_cnt[257];
  __shared__ int   s_mode;
  __shared__ int   s_ntrue;
  __shared__ int   s_sel[MLEN];        // 8 KB
  __shared__ float s_e[MLEN];          // 8 KB

  if (tid == 0) {
    unsigned w0 = ((const unsigned*)bmask_raw)[0];
    s_mode = (w0 <= 1u) ? 1 : 0;  // 1: int32 per element, 0: uint8 per element
  }
  __syncthreads();
  const int mode = s_mode;
  const unsigned char* bmask_u8 = (const unsigned char*)bmask_raw;

  const int PER = LFULL / 256;    // 16 positions per thread
  const int base = tid * PER;

  int cnt = 0;
  for (int i = 0; i < PER; ++i) {
    const int L = base + i;
    const int v = mode ? (bmask_raw[b * LFULL + L] != 0)
                       : (bmask_u8[b * LFULL + L] != 0);
    cnt += v;
  }
  s_cnt[tid] = cnt;
  __syncthreads();

  // Exclusive prefix over 256 counts: wave 0, lane i owns entries 4i..4i+3.
  if (tid < 64) {
    const int j = tid * 4;
    const int c0 = s_cnt[j], c1 = s_cnt[j + 1], c2 = s_cnt[j + 2], c3 = s_cnt[j + 3];
    const int mysum = c0 + c1 + c2 + c3;
    int incl = mysum;
    #pragma unroll
    for (int off = 1; off < 64; off <<= 1) {
      const int v = __shfl_up(incl, off, 64);
      if (tid >= off) incl += v;
    }
    const int excl = incl - mysum;
    s_cnt[j]     = excl;
    s_cnt[j + 1] = excl + c0;
    s_cnt[j + 2] = excl + c0 + c1;
    s_cnt[j + 3] = excl + c0 + c1 + c2;
    if (tid == 63) { s_cnt[256] = incl; s_ntrue = incl; }
  }
  __syncthreads();
  const int ntrue = s_ntrue;

  // Fill sel: boundary positions (rank) then non-boundary (ntrue + false-rank)
  int trun = s_cnt[tid];
  for (int i = 0; i < PER; ++i) {
    const int L = base + i;
    const int v = mode ? (bmask_raw[b * LFULL + L] != 0)
                       : (bmask_u8[b * LFULL + L] != 0);
    if (v) {
      if (trun < MLEN) s_sel[trun] = L;
      ++trun;
    } else {
      const int f = L - trun;           // falses strictly before L
      const int slot = ntrue + f;
      if (slot < MLEN) s_sel[slot] = L;
    }
  }
  __syncthreads();

  // w, e per selected position
  for (int j = tid; j < MLEN; j += 256) {
    const int L = s_sel[j];
    float p = bprob[((size_t)b * LFULL + L) * 2 + 1];
    p = fminf(fmaxf(p, CLIP_EPS), 1.0f - CLIP_EPS);
    const float dt = -log1pf(-p);       // log(1/(1-p))
    wA[b * MLEN + j] = p / dt;
    const float e = 1.0f - p;           // exp(-dt) exactly
    eA[b * MLEN + j] = e;
    s_e[j] = e;
  }
  __syncthreads();

  // per-chunk cumulative decay + chunk product: one thread per chunk of 8
  {
    const int c = tid;                  // 256 chunks
    const int o = c * TCH;
    float run = 1.0f;
    #pragma unroll
    for (int i = 0; i < TCH; ++i) {
      run *= s_e[o + i];
      cde[b * MLEN + o + i] = run;
    }
    Pc[b * CCH + c] = run;
  }

  // scatter ranges: plug[L] = (#boundaries <= L) - 1, clamped to [0, M-1]
  const int nb = (ntrue < MLEN) ? ntrue : MLEN;
  for (int j = tid; j < MLEN; j += 256) {
    int ls, le;
    if (nb == 0) {
      ls = (j == 0) ? 0 : LFULL;
      le = (j == 0) ? LFULL : LFULL;
    } else if (j < nb) {
      ls = (j == 0) ? 0 : s_sel[j];
      le = (j == nb - 1) ? LFULL : s_sel[j + 1];
    } else {
      ls = LFULL; le = LFULL;           // empty
    }
    Ls[b * MLEN + j] = ls;
    Le[b * MLEN + j] = le;
  }
}

// ---------------------------------------------------------------------------
// K2B: fused local-scan + cross-chunk scan + output scatter.
//   block = (column strip of 16 floats, batch); 1024 threads = 256 chunks x
//   4 f4-lanes. All 256 chunks are in ONE block, so the cross-chunk scan is
//   a block-local LDS Hillis-Steele (bit-identical arithmetic to k25_scan).
//   Per-position local states are kept in registers (xr[t]), so hid is read
//   exactly once and there is NO global S traffic at all.
//   Coalescing: per wave = 16 chunks x (4 lanes x 16 B contiguous) = full
//   64 B segments, zero overfetch.
// grid: (DMODEL/16, BSZ) = (128, 2) = 256 blocks x 1024 threads
// ---------------------------------------------------------------------------
__global__ __launch_bounds__(1024, 4) void k2b_fused(
    const float* __restrict__ hid, const float* __restrict__ wA,
    const float* __restrict__ eA, const float* __restrict__ cde,
    const float* __restrict__ Pc,
    const int* __restrict__ Ls, const int* __restrict__ Le,
    float* __restrict__ out)
{
  const int tid = threadIdx.x;
  const int j   = tid & 3;          // f4 lane within the 16-float strip
  const int c   = tid >> 2;         // chunk [0, 256)
  const int bx  = blockIdx.x;       // strip [0, 128)
  const int b   = blockIdx.y;       // batch

  __shared__ float sP[CCH];         // 1 KB
  __shared__ f4    sS[CCH][4];      // 16 KB

  const int d4 = bx * 4 + j;        // f4 column index [0, 512)
  const int o  = b * MLEN + c * TCH;

  // ---- phase 1: local chunk scan; keep per-position states in regs ----
  const f4* xp = (const f4*)hid + ((size_t)o * DMODEL >> 2) + d4;
  f4 xr[TCH];
  f4 st = {0.f, 0.f, 0.f, 0.f};
  #pragma unroll
  for (int t = 0; t < TCH; ++t) {
    const f4 x = xp[(size_t)t * (DMODEL / 4)];
    const float w = wA[o + t], e = eA[o + t];
    st.x = fmaf(e, st.x, w * x.x);
    st.y = fmaf(e, st.y, w * x.y);
    st.z = fmaf(e, st.z, w * x.z);
    st.w = fmaf(e, st.w, w * x.w);
    xr[t] = st;                     // running local state at position t
  }
  sS[c][j] = st;
  if (j == 0) sP[c] = Pc[b * CCH + c];
  __syncthreads();

  // ---- phase 2: Hillis-Steele over 256 chunks (same math as k25_scan) ----
  for (int dstep = 1; dstep < CCH; dstep <<= 1) {
    // read everything BEFORE the barrier (4 threads share sP[c]; only j==0
    // writes it, so the read must happen in the read phase)
    const float pc = sP[c];
    float pd = 1.0f;
    f4 sd = {0.f, 0.f, 0.f, 0.f};
    if (c >= dstep) { pd = sP[c - dstep]; sd = sS[c - dstep][j]; }
    __syncthreads();
    if (c >= dstep) {
      f4 cur = sS[c][j];            // own entry: no writer conflict
      cur.x = fmaf(pc, sd.x, cur.x);
      cur.y = fmaf(pc, sd.y, cur.y);
      cur.z = fmaf(pc, sd.z, cur.z);
      cur.w = fmaf(pc, sd.w, cur.w);
      sS[c][j] = cur;
      if (j == 0) sP[c] = pc * pd;
    }
    __syncthreads();
  }

  // exclusive shift: carry-in for chunk c is inclusive scan at c-1
  f4 H = {0.f, 0.f, 0.f, 0.f};
  if (c > 0) H = sS[c - 1][j];

  // ---- phase 3: y = xr + cde*H, NT scatter to out rows [Ls, Le) ----
  f4* op = (f4*)out + ((size_t)b * LFULL * DMODEL >> 2) + d4;
  #pragma unroll
  for (int t = 0; t < TCH; ++t) {
    const float cd = cde[o + t];
    f4 y;
    y.x = fmaf(cd, H.x, xr[t].x);
    y.y = fmaf(cd, H.y, xr[t].y);
    y.z = fmaf(cd, H.z, xr[t].z);
    y.w = fmaf(cd, H.w, xr[t].w);
    const int ls = Ls[o + t], le = Le[o + t];
    for (int L = ls; L < le; ++L) {
      __builtin_nontemporal_store(y, op + (size_t)L * (DMODEL / 4));
    }
  }
}

// ---------------------------------------------------------------------------
extern "C" void kernel_launch(void* const* d_in, const int* in_sizes, int n_in,
                              void* d_out, int out_size, void* d_ws, size_t ws_size,
                              hipStream_t stream) {
  const float* hid   = (const float*)d_in[0];   // (2, 2048, 2048) fp32
  const int*   bmask = (const int*)d_in[1];     // (2, 4096) bool (layout sniffed)
  const float* bprob = (const float*)d_in[2];   // (2, 4096, 2) fp32
  float*       out   = (float*)d_out;           // (2, 4096, 2048) fp32

  char* ws = (char*)d_ws;
  const size_t SZI = (size_t)BSZ * MLEN * sizeof(int);    // 16 KB
  const size_t SZF = (size_t)BSZ * MLEN * sizeof(float);  // 16 KB
  int*   Ls  = (int*)(ws);
  int*   Le  = (int*)(ws + SZI);
  float* wA  = (float*)(ws + 2 * SZI);
  float* eA  = (float*)(ws + 2 * SZI + SZF);
  float* cde = (float*)(ws + 2 * SZI + 2 * SZF);
  float* Pc  = (float*)(ws + 2 * SZI + 3 * SZF);          // 2 KB used

  k1_prep<<<dim3(BSZ), dim3(256), 0, stream>>>(bmask, bprob, Ls, Le, wA, eA, cde, Pc);

  k2b_fused<<<dim3(DMODEL / 16, BSZ), dim3(1024), 0, stream>>>(
      hid, wA, eA, cde, Pc, Ls, Le, out);
}